// Round 4
// baseline (3706.177 us; speedup 1.0000x reference)
//
#include <hip/hip_runtime.h>
#include <hip/hip_bf16.h>

// Problem constants (from reference)
#define NN 100000      // nodes
#define FF 128         // F_IN
#define HH 64          // HID
#define BN_EPS 1e-5f

// Blocked-SpMM geometry
#define TILE 240                          // dst nodes per workgroup (LDS acc)
#define NT   ((NN + TILE - 1) / TILE)     // 417 dst tiles (all co-resident, 2/CU)
#define SBLK 8192                         // src rows per block (2 MB of h rows)
#define NBLK ((NN + SBLK - 1) / SBLK)     // 13 src blocks
#define NKEY (NT * NBLK)                  // 5421 (tile, block) buckets

// ---------------- dtype detection (int64 vs int32 edge/batch) ----------------
__global__ void k_detect(const unsigned* __restrict__ ei, int* __restrict__ flag) {
    if (threadIdx.x == 0 && blockIdx.x == 0) {
        unsigned o = 0;
        for (int i = 1; i < 32; i += 2) o |= ei[i];   // high words if int64
        *flag = (o == 0) ? 1 : 0;                      // 1 => int64
    }
}

__device__ __forceinline__ int load_idx(const void* p, int i, int is64) {
    return is64 ? (int)((const long long*)p)[i] : ((const int*)p)[i];
}

// ---------------- degree count + (tile,block) bucket count ----------------
__global__ void k_count(const void* __restrict__ ei, int E, const int* __restrict__ flag,
                        int* __restrict__ counts, int* __restrict__ counts2) {
    int e = blockIdx.x * blockDim.x + threadIdx.x;
    if (e >= E) return;
    int is64 = *flag;
    int s = load_idx(ei, e, is64);
    int d = load_idx(ei, E + e, is64);
    atomicAdd(&counts[d], 1);
    int key = (d / TILE) * NBLK + (s >> 13);   // SBLK = 8192 = 1<<13
    atomicAdd(&counts2[key], 1);
}

// ---------------- dinv + per-graph node counts ----------------
__global__ void k_dinv(const int* __restrict__ counts, float* __restrict__ dinv,
                       const void* __restrict__ bat, const int* __restrict__ flag,
                       int* __restrict__ gcnt, int N) {
    int i = blockIdx.x * blockDim.x + threadIdx.x;
    if (i >= N) return;
    float deg = (float)counts[i] + 1.0f;
    dinv[i] = rsqrtf(deg);
    int is64 = *flag;
    int b = load_idx(bat, i, is64);
    atomicAdd(&gcnt[b], 1);
}

// ---------------- 3-kernel exclusive scan (chunk = 512) ----------------
__global__ void k_scan1(const int* __restrict__ counts, int* __restrict__ partial, int N) {
    __shared__ int s[512];
    int t = threadIdx.x;
    int i = blockIdx.x * 512 + t;
    int v = (i < N) ? counts[i] : 0;
    s[t] = v; __syncthreads();
    for (int off = 256; off; off >>= 1) {
        if (t < off) s[t] += s[t + off];
        __syncthreads();
    }
    if (t == 0) partial[blockIdx.x] = s[0];
}

__global__ void k_scan2(int* __restrict__ partial, int nch) {
    __shared__ int s[256];
    int t = threadIdx.x;
    int v = (t < nch) ? partial[t] : 0;
    s[t] = v; __syncthreads();
    for (int off = 1; off < 256; off <<= 1) {
        int add = (t >= off) ? s[t - off] : 0;
        __syncthreads();
        s[t] += add;
        __syncthreads();
    }
    if (t < nch) partial[t] = s[t] - v;   // exclusive
}

__global__ void k_scan3(const int* __restrict__ counts, const int* __restrict__ partial,
                        int* __restrict__ rp, int N, int E) {
    __shared__ int s[512];
    int t = threadIdx.x;
    int i = blockIdx.x * 512 + t;
    int v = (i < N) ? counts[i] : 0;
    s[t] = v; __syncthreads();
    for (int off = 1; off < 512; off <<= 1) {
        int add = (t >= off) ? s[t - off] : 0;
        __syncthreads();
        s[t] += add;
        __syncthreads();
    }
    if (i < N) rp[i] = partial[blockIdx.x] + s[t] - v;
    if (i == N) rp[N] = E;
}

// ---------------- bucket fill: packed {src | dlocal<<17, w} ----------------
__global__ void k_fill2(const void* __restrict__ ei, int E, const int* __restrict__ flag,
                        const float* __restrict__ dinv, const int* __restrict__ rp2,
                        int* __restrict__ fill2, int2* __restrict__ cw2) {
    int e = blockIdx.x * blockDim.x + threadIdx.x;
    if (e >= E) return;
    int is64 = *flag;
    int s = load_idx(ei, e, is64);
    int d = load_idx(ei, E + e, is64);
    float w = dinv[s] * dinv[d];
    int tile = d / TILE;
    int key = tile * NBLK + (s >> 13);
    int dl = d - tile * TILE;                 // < 240, fits 8 bits
    int pos = rp2[key] + atomicAdd(&fill2[key], 1);
    int2 p; p.x = s | (dl << 17); p.y = __float_as_int(w);
    cw2[pos] = p;
}

// ---------------- BN constant folding ----------------
__global__ void k_prep(const float* b1, const float* g1, const float* be1,
                       const float* m1, const float* v1,
                       const float* b2, const float* g2, const float* be2,
                       const float* m2, const float* v2,
                       float* sc1, float* sh1, float* sc2, float* sh2) {
    int f = threadIdx.x;
    if (f < HH) {
        float s1 = g1[f] * rsqrtf(v1[f] + BN_EPS);
        sc1[f] = s1; sh1[f] = (b1[f] - m1[f]) * s1 + be1[f];
        float s2 = g2[f] * rsqrtf(v2[f] + BN_EPS);
        sc2[f] = s2; sh2[f] = (b2[f] - m2[f]) * s2 + be2[f];
    }
}

// ---------------- dense GEMM: out[n][f] = sum_k x[n][k] * W[f][k] ----------------
template <int K, int NPB>
__global__ void k_gemm(const float* __restrict__ x, const float* __restrict__ W,
                       float* __restrict__ out, int N) {
    __shared__ float wT[K * (HH + 1)];
    __shared__ float xs[NPB * K];
    const int TB = NPB * 64;
    int t = threadIdx.x;
    for (int idx = t; idx < K * HH; idx += TB) {
        int f = idx / K, k = idx % K;
        wT[k * (HH + 1) + f] = W[idx];
    }
    int nb = blockIdx.x * NPB;
    for (int idx = t; idx < NPB * K; idx += TB) {
        int gi = nb * K + idx;
        xs[idx] = (gi < N * K) ? x[gi] : 0.0f;
    }
    __syncthreads();
    int f = t & 63, nl = t >> 6;
    float acc = 0.0f;
#pragma unroll
    for (int k = 0; k < K; k++)
        acc += xs[nl * K + k] * wT[k * (HH + 1) + f];
    int n = nb + nl;
    if (n < N) out[n * HH + f] = acc;
}

// ---------------- blocked aggregation: dst-tile acc in LDS, src L2-blocked ----
// One WG per 240-dst tile (417 WGs, all co-resident at 2 WG/CU). Loop over 13
// source blocks of 8192 rows (2 MB) -> all WGs gather from the same hot block
// -> L2-hit gathers instead of LLC-latency misses. Accumulate via ds_add_f32.
template <int LAYER>
__global__ __launch_bounds__(256, 2) void k_agg2(
        const float* __restrict__ h, const int2* __restrict__ cw2,
        const int* __restrict__ rp2, const float* __restrict__ dinv,
        const float* __restrict__ sc, const float* __restrict__ sh,
        float* __restrict__ out, const void* __restrict__ bat,
        const int* __restrict__ flag, const float* __restrict__ Wl,
        float* __restrict__ gsum, int N) {
    __shared__ float acc[TILE * 65];           // stride 65 floats: bank-friendly
    const float4* __restrict__ h4 = (const float4*)h;
    int tile = blockIdx.x, d0 = tile * TILE, t = threadIdx.x;

    // init: self-loop term dinv^2 * h[d]
    for (int idx = t; idx < TILE * 16; idx += 256) {
        int dl = idx >> 4, fl = idx & 15, d = d0 + dl;
        float4 v = make_float4(0.f, 0.f, 0.f, 0.f);
        if (d < N) {
            float di = dinv[d]; float s2 = di * di;
            float4 r = h4[d * 16 + fl];
            v.x = r.x * s2; v.y = r.y * s2; v.z = r.z * s2; v.w = r.w * s2;
        }
        int base = dl * 65 + fl * 4;
        acc[base + 0] = v.x; acc[base + 1] = v.y;
        acc[base + 2] = v.z; acc[base + 3] = v.w;
    }
    __syncthreads();

    int w = t >> 6, lane = t & 63, q = lane >> 4, fl = lane & 15;
    for (int b = 0; b < NBLK; b++) {
        int kk = tile * NBLK + b;
        int s0 = rp2[kk], e0 = rp2[kk + 1];
        int len = e0 - s0;
        int ws = s0 + ((len * w) >> 2);
        int we = s0 + ((len * (w + 1)) >> 2);
        for (int j = ws; j < we; j += 16) {     // 16 edges per wave-iter
            int2 p[4]; int vld[4];
#pragma unroll
            for (int u = 0; u < 4; u++) {
                int jj = j + u * 4 + q;
                vld[u] = jj < we;
                int xi = vld[u] ? jj : (we - 1);
                p[u] = cw2[xi];
            }
#pragma unroll
            for (int u = 0; u < 4; u++) {
                float wgt = vld[u] ? __int_as_float(p[u].y) : 0.f;
                int src = p[u].x & 0x1FFFF;
                int dl = p[u].x >> 17;
                float4 r = h4[src * 16 + fl];
                int base = dl * 65 + fl * 4;
                atomicAdd(&acc[base + 0], wgt * r.x);
                atomicAdd(&acc[base + 1], wgt * r.y);
                atomicAdd(&acc[base + 2], wgt * r.z);
                atomicAdd(&acc[base + 3], wgt * r.w);
            }
        }
    }
    __syncthreads();

    if (LAYER == 1) {
        for (int idx = t; idx < TILE * 16; idx += 256) {
            int dl = idx >> 4, f4 = idx & 15, d = d0 + dl;
            if (d < N) {
                int base = dl * 65 + f4 * 4; int f0 = f4 * 4;
                float4 o;
                o.x = fmaxf(acc[base + 0] * sc[f0 + 0] + sh[f0 + 0], 0.f);
                o.y = fmaxf(acc[base + 1] * sc[f0 + 1] + sh[f0 + 1], 0.f);
                o.z = fmaxf(acc[base + 2] * sc[f0 + 2] + sh[f0 + 2], 0.f);
                o.w = fmaxf(acc[base + 3] * sc[f0 + 3] + sh[f0 + 3], 0.f);
                ((float4*)out)[d * 16 + f4] = o;
            }
        }
    } else {
        int is64 = *flag;
        int f4 = t & 15, f0 = f4 * 4;
        for (int dl = (t >> 4); dl < TILE; dl += 16) {
            int d = d0 + dl;
            float tv = 0.f;
            if (d < N) {
                int base = dl * 65 + f0;
                float a0 = fmaxf(acc[base + 0] * sc[f0 + 0] + sh[f0 + 0], 0.f);
                float a1 = fmaxf(acc[base + 1] * sc[f0 + 1] + sh[f0 + 1], 0.f);
                float a2 = fmaxf(acc[base + 2] * sc[f0 + 2] + sh[f0 + 2], 0.f);
                float a3 = fmaxf(acc[base + 3] * sc[f0 + 3] + sh[f0 + 3], 0.f);
                tv = a0 * Wl[f0] + a1 * Wl[f0 + 1] + a2 * Wl[f0 + 2] + a3 * Wl[f0 + 3];
            }
            tv += __shfl_xor(tv, 1);
            tv += __shfl_xor(tv, 2);
            tv += __shfl_xor(tv, 4);
            tv += __shfl_xor(tv, 8);
            if (f4 == 0 && d < N) {
                int bg = load_idx(bat, d, is64);
                atomicAdd(&gsum[bg], tv);
            }
        }
    }
}

// ---------------- final: mean + linear bias ----------------
__global__ void k_final(const float* __restrict__ gsum, const int* __restrict__ gcnt,
                        const float* __restrict__ bl, float* __restrict__ outp, int G) {
    int g = blockIdx.x * blockDim.x + threadIdx.x;
    if (g < G) outp[g] = gsum[g] / fmaxf((float)gcnt[g], 1.0f) + bl[0];
}

extern "C" void kernel_launch(void* const* d_in, const int* in_sizes, int n_in,
                              void* d_out, int out_size, void* d_ws, size_t ws_size,
                              hipStream_t stream) {
    const float* x   = (const float*)d_in[0];
    const void*  ei  = d_in[1];
    const void*  bat = d_in[2];
    const float* W1  = (const float*)d_in[3];
    const float* b1  = (const float*)d_in[4];
    const float* g1  = (const float*)d_in[5];
    const float* be1 = (const float*)d_in[6];
    const float* m1  = (const float*)d_in[7];
    const float* v1  = (const float*)d_in[8];
    const float* W2  = (const float*)d_in[9];
    const float* b2  = (const float*)d_in[10];
    const float* g2  = (const float*)d_in[11];
    const float* be2 = (const float*)d_in[12];
    const float* m2  = (const float*)d_in[13];
    const float* v2  = (const float*)d_in[14];
    const float* Wl  = (const float*)d_in[15];
    const float* bl  = (const float*)d_in[16];
    float* outp = (float*)d_out;

    const int N = NN;
    const int E = in_sizes[1] / 2;
    const int G = out_size;

    // workspace carve-up (256B aligned)
    char* base = (char*)d_ws;
    size_t off = 0;
    auto alloc = [&](size_t bytes) { void* p = base + off; off = (off + bytes + 255) & ~(size_t)255; return p; };
    int*   flag    = (int*)  alloc(16);
    float* dinv    = (float*)alloc((size_t)N * 4);
    int*   counts  = (int*)  alloc((size_t)N * 4);
    int*   counts2 = (int*)  alloc((size_t)NKEY * 4);
    int*   fill2   = (int*)  alloc((size_t)NKEY * 4);
    int*   rp2     = (int*)  alloc(((size_t)NKEY + 1) * 4);
    int*   partial = (int*)  alloc(4096);
    float* sc1     = (float*)alloc(HH * 4);
    float* sh1     = (float*)alloc(HH * 4);
    float* sc2     = (float*)alloc(HH * 4);
    float* sh2     = (float*)alloc(HH * 4);
    float* gsum    = (float*)alloc((size_t)G * 4);
    int*   gcnt    = (int*)  alloc((size_t)G * 4);
    int2*  cw2     = (int2*) alloc((size_t)E * 8);
    float* bufA    = (float*)alloc((size_t)N * HH * 4);
    float* bufB    = (float*)alloc((size_t)N * HH * 4);
    (void)ws_size;

    // zero accumulators (fresh every call)
    hipMemsetAsync(counts, 0, (size_t)N * 4, stream);
    hipMemsetAsync(counts2, 0, (size_t)NKEY * 4, stream);
    hipMemsetAsync(fill2, 0, (size_t)NKEY * 4, stream);
    hipMemsetAsync(gsum, 0, (size_t)G * 4, stream);
    hipMemsetAsync(gcnt, 0, (size_t)G * 4, stream);

    k_detect<<<1, 64, 0, stream>>>((const unsigned*)ei, flag);

    int eb = (E + 255) / 256;
    k_count<<<eb, 256, 0, stream>>>(ei, E, flag, counts, counts2);

    int nb = (N + 255) / 256;
    k_dinv<<<nb, 256, 0, stream>>>(counts, dinv, bat, flag, gcnt, N);

    int kch = (NKEY + 511) / 512;               // 11 chunks covers NKEY and NKEY+1
    k_scan1<<<kch, 512, 0, stream>>>(counts2, partial, NKEY);
    k_scan2<<<1, 256, 0, stream>>>(partial, kch);
    k_scan3<<<kch, 512, 0, stream>>>(counts2, partial, rp2, NKEY, E);

    k_fill2<<<eb, 256, 0, stream>>>(ei, E, flag, dinv, rp2, fill2, cw2);

    k_prep<<<1, 64, 0, stream>>>(b1, g1, be1, m1, v1, b2, g2, be2, m2, v2,
                                 sc1, sh1, sc2, sh2);

    // layer 1
    k_gemm<FF, 8><<<(N + 7) / 8, 512, 0, stream>>>(x, W1, bufA, N);
    k_agg2<1><<<NT, 256, 0, stream>>>(bufA, cw2, rp2, dinv, sc1, sh1, bufB,
                                      bat, flag, Wl, gsum, N);
    // layer 2
    k_gemm<HH, 8><<<(N + 7) / 8, 512, 0, stream>>>(bufB, W2, bufA, N);
    k_agg2<2><<<NT, 256, 0, stream>>>(bufA, cw2, rp2, dinv, sc2, sh2, nullptr,
                                      bat, flag, Wl, gsum, N);

    k_final<<<1, 256, 0, stream>>>(gsum, gcnt, bl, outp, G);
}

// Round 5
// 1276.810 us; speedup vs baseline: 2.9027x; 2.9027x over previous
//
#include <hip/hip_runtime.h>
#include <hip/hip_bf16.h>

// Problem constants (from reference)
#define NN 100000      // nodes
#define FF 128         // F_IN
#define HH 64          // HID
#define BN_EPS 1e-5f

typedef unsigned int uint_t;

// ---------------- bf16 helpers (RNE) ----------------
__device__ __forceinline__ float bflo(uint_t u) { return __uint_as_float(u << 16); }
__device__ __forceinline__ float bfhi(uint_t u) { return __uint_as_float(u & 0xFFFF0000u); }
__device__ __forceinline__ unsigned short f2bf(float f) {
    uint_t a = __float_as_uint(f); a += 0x7FFF + ((a >> 16) & 1); return (unsigned short)(a >> 16);
}
__device__ __forceinline__ uint_t f2bf2(float lo, float hi) {
    uint_t a = __float_as_uint(lo); a += 0x7FFF + ((a >> 16) & 1);
    uint_t b = __float_as_uint(hi); b += 0x7FFF + ((b >> 16) & 1);
    return (a >> 16) | (b & 0xFFFF0000u);
}

// ---------------- dtype detection (int64 vs int32 edge/batch) ----------------
__global__ void k_detect(const unsigned* __restrict__ ei, int* __restrict__ flag) {
    if (threadIdx.x == 0 && blockIdx.x == 0) {
        unsigned o = 0;
        for (int i = 1; i < 32; i += 2) o |= ei[i];   // high words if int64
        *flag = (o == 0) ? 1 : 0;                      // 1 => int64
    }
}

__device__ __forceinline__ int load_idx(const void* p, int i, int is64) {
    return is64 ? (int)((const long long*)p)[i] : ((const int*)p)[i];
}

// ---------------- degree count ----------------
__global__ void k_count(const void* __restrict__ ei, int E, const int* __restrict__ flag,
                        int* __restrict__ counts) {
    int e = blockIdx.x * blockDim.x + threadIdx.x;
    if (e >= E) return;
    int is64 = *flag;
    int d = load_idx(ei, E + e, is64);   // dst row is second half
    atomicAdd(&counts[d], 1);
}

// ---------------- dinv + per-graph node counts ----------------
__global__ void k_dinv(const int* __restrict__ counts, float* __restrict__ dinv,
                       const void* __restrict__ bat, const int* __restrict__ flag,
                       int* __restrict__ gcnt, int N) {
    int i = blockIdx.x * blockDim.x + threadIdx.x;
    if (i >= N) return;
    float deg = (float)counts[i] + 1.0f;
    dinv[i] = rsqrtf(deg);
    int is64 = *flag;
    int b = load_idx(bat, i, is64);
    atomicAdd(&gcnt[b], 1);
}

// ---------------- 3-kernel exclusive scan (chunk = 512) ----------------
__global__ void k_scan1(const int* __restrict__ counts, int* __restrict__ partial, int N) {
    __shared__ int s[512];
    int t = threadIdx.x;
    int i = blockIdx.x * 512 + t;
    int v = (i < N) ? counts[i] : 0;
    s[t] = v; __syncthreads();
    for (int off = 256; off; off >>= 1) {
        if (t < off) s[t] += s[t + off];
        __syncthreads();
    }
    if (t == 0) partial[blockIdx.x] = s[0];
}

__global__ void k_scan2(int* __restrict__ partial, int nch) {
    __shared__ int s[256];
    int t = threadIdx.x;
    int v = (t < nch) ? partial[t] : 0;
    s[t] = v; __syncthreads();
    for (int off = 1; off < 256; off <<= 1) {
        int add = (t >= off) ? s[t - off] : 0;
        __syncthreads();
        s[t] += add;
        __syncthreads();
    }
    if (t < nch) partial[t] = s[t] - v;   // exclusive
}

__global__ void k_scan3(const int* __restrict__ counts, const int* __restrict__ partial,
                        int* __restrict__ rp, int N, int E) {
    __shared__ int s[512];
    int t = threadIdx.x;
    int i = blockIdx.x * 512 + t;
    int v = (i < N) ? counts[i] : 0;
    s[t] = v; __syncthreads();
    for (int off = 1; off < 512; off <<= 1) {
        int add = (t >= off) ? s[t - off] : 0;
        __syncthreads();
        s[t] += add;
        __syncthreads();
    }
    if (i < N) rp[i] = partial[blockIdx.x] + s[t] - v;
    if (i == N) rp[N] = E;
}

// ---------------- CSR fill: packed {src, w} ----------------
__global__ void k_fill(const void* __restrict__ ei, int E, const int* __restrict__ flag,
                       const float* __restrict__ dinv, const int* __restrict__ rp,
                       int* __restrict__ fillcnt, int2* __restrict__ cw) {
    int e = blockIdx.x * blockDim.x + threadIdx.x;
    if (e >= E) return;
    int is64 = *flag;
    int s = load_idx(ei, e, is64);
    int d = load_idx(ei, E + e, is64);
    float w = dinv[s] * dinv[d];
    int pos = rp[d] + atomicAdd(&fillcnt[d], 1);
    int2 p; p.x = s; p.y = __float_as_int(w);
    cw[pos] = p;
}

// ---------------- BN constant folding ----------------
__global__ void k_prep(const float* b1, const float* g1, const float* be1,
                       const float* m1, const float* v1,
                       const float* b2, const float* g2, const float* be2,
                       const float* m2, const float* v2,
                       float* sc1, float* sh1, float* sc2, float* sh2) {
    int f = threadIdx.x;
    if (f < HH) {
        float s1 = g1[f] * rsqrtf(v1[f] + BN_EPS);
        sc1[f] = s1; sh1[f] = (b1[f] - m1[f]) * s1 + be1[f];
        float s2 = g2[f] * rsqrtf(v2[f] + BN_EPS);
        sc2[f] = s2; sh2[f] = (b2[f] - m2[f]) * s2 + be2[f];
    }
}

// ---------------- dense GEMM: out[n][f] = bf16(sum_k x[n][k] * W[f][k]) ----------
__device__ __forceinline__ float ldf(const float* p, int i) { return p[i]; }
__device__ __forceinline__ float ldf(const unsigned short* p, int i) {
    return __uint_as_float((uint_t)p[i] << 16);
}

template <int K, int NPB, typename Tin>
__global__ void k_gemm(const Tin* __restrict__ x, const float* __restrict__ W,
                       unsigned short* __restrict__ out, int N) {
    __shared__ float wT[K * (HH + 1)];
    __shared__ float xs[NPB * K];
    const int TB = NPB * 64;
    int t = threadIdx.x;
    for (int idx = t; idx < K * HH; idx += TB) {
        int f = idx / K, k = idx % K;
        wT[k * (HH + 1) + f] = W[idx];
    }
    int nb = blockIdx.x * NPB;
    for (int idx = t; idx < NPB * K; idx += TB) {
        int gi = nb * K + idx;
        xs[idx] = (gi < N * K) ? ldf(x, gi) : 0.0f;
    }
    __syncthreads();
    int f = t & 63, nl = t >> 6;
    float acc = 0.0f;
#pragma unroll
    for (int k = 0; k < K; k++)
        acc += xs[nl * K + k] * wT[k * (HH + 1) + f];
    int n = nb + nl;
    if (n < N) out[n * HH + f] = f2bf(acc);
}

// ---------------- aggregation (wave per node, bf16 gather, 16 edges in flight) --
// Lane layout: q = lane>>4 (edge slot), fl = lane&15 (uint2 = 4 bf16 of the row).
// Row = 128 B (2 cache lines). 16 independent row-gathers in flight per wave.
template <int LAYER>
__global__ void k_agg(const unsigned short* __restrict__ h, const int2* __restrict__ cw,
                      const int* __restrict__ rp, const float* __restrict__ dinv,
                      const float* __restrict__ sc, const float* __restrict__ sh,
                      unsigned short* __restrict__ out,
                      const void* __restrict__ bat, const int* __restrict__ flag,
                      const float* __restrict__ Wl, float* __restrict__ gsum, int N) {
    int wid = (int)((blockIdx.x * blockDim.x + threadIdx.x) >> 6);
    if (wid >= N) return;
    int lane = threadIdx.x & 63;
    int q = lane >> 4;       // which edge within the 4-edge group
    int fl = lane & 15;      // which uint2 (4 bf16) of the row
    const uint2* __restrict__ h2 = (const uint2*)h;

    int s = rp[wid], e = rp[wid + 1];
    float a0 = 0.f, a1 = 0.f, a2 = 0.f, a3 = 0.f;
    if (e > s) {
        int last = e - 1;
        for (int j0 = s; j0 < e; j0 += 16) {
            int2 p[4]; float w[4];
#pragma unroll
            for (int u = 0; u < 4; u++) {
                int jj = j0 + u * 4 + q;
                p[u] = cw[jj < last ? jj : last];
                w[u] = (jj < e) ? __int_as_float(p[u].y) : 0.f;
            }
#pragma unroll
            for (int u = 0; u < 4; u++) {
                uint2 r = h2[p[u].x * 16 + fl];
                a0 += w[u] * bflo(r.x);
                a1 += w[u] * bfhi(r.x);
                a2 += w[u] * bflo(r.y);
                a3 += w[u] * bfhi(r.y);
            }
        }
    }
    // combine the 4 edge-partitions (lanes differing in bits 4,5)
    a0 += __shfl_xor(a0, 16); a1 += __shfl_xor(a1, 16);
    a2 += __shfl_xor(a2, 16); a3 += __shfl_xor(a3, 16);
    a0 += __shfl_xor(a0, 32); a1 += __shfl_xor(a1, 32);
    a2 += __shfl_xor(a2, 32); a3 += __shfl_xor(a3, 32);

    // self-loop term (added once, post-reduce)
    float di = dinv[wid];
    float di2 = di * di;
    uint2 sr = h2[wid * 16 + fl];
    a0 += di2 * bflo(sr.x); a1 += di2 * bfhi(sr.x);
    a2 += di2 * bflo(sr.y); a3 += di2 * bfhi(sr.y);

    // BN + ReLU on this lane's 4 features
    int f0 = fl * 4;
    float v0 = fmaxf(a0 * sc[f0 + 0] + sh[f0 + 0], 0.f);
    float v1 = fmaxf(a1 * sc[f0 + 1] + sh[f0 + 1], 0.f);
    float v2 = fmaxf(a2 * sc[f0 + 2] + sh[f0 + 2], 0.f);
    float v3 = fmaxf(a3 * sc[f0 + 3] + sh[f0 + 3], 0.f);

    if (LAYER == 1) {
        if (lane < 16) {
            uint2 o; o.x = f2bf2(v0, v1); o.y = f2bf2(v2, v3);
            ((uint2*)out)[wid * 16 + fl] = o;
        }
    } else {
        float tval = v0 * Wl[f0] + v1 * Wl[f0 + 1] + v2 * Wl[f0 + 2] + v3 * Wl[f0 + 3];
        tval += __shfl_xor(tval, 1);
        tval += __shfl_xor(tval, 2);
        tval += __shfl_xor(tval, 4);
        tval += __shfl_xor(tval, 8);
        if (lane == 0) {
            int is64 = *flag;
            int b = load_idx(bat, wid, is64);
            atomicAdd(&gsum[b], tval);
        }
    }
}

// ---------------- final: mean + linear bias ----------------
__global__ void k_final(const float* __restrict__ gsum, const int* __restrict__ gcnt,
                        const float* __restrict__ bl, float* __restrict__ outp, int G) {
    int g = blockIdx.x * blockDim.x + threadIdx.x;
    if (g < G) outp[g] = gsum[g] / fmaxf((float)gcnt[g], 1.0f) + bl[0];
}

extern "C" void kernel_launch(void* const* d_in, const int* in_sizes, int n_in,
                              void* d_out, int out_size, void* d_ws, size_t ws_size,
                              hipStream_t stream) {
    const float* x   = (const float*)d_in[0];
    const void*  ei  = d_in[1];
    const void*  bat = d_in[2];
    const float* W1  = (const float*)d_in[3];
    const float* b1  = (const float*)d_in[4];
    const float* g1  = (const float*)d_in[5];
    const float* be1 = (const float*)d_in[6];
    const float* m1  = (const float*)d_in[7];
    const float* v1  = (const float*)d_in[8];
    const float* W2  = (const float*)d_in[9];
    const float* b2  = (const float*)d_in[10];
    const float* g2  = (const float*)d_in[11];
    const float* be2 = (const float*)d_in[12];
    const float* m2  = (const float*)d_in[13];
    const float* v2  = (const float*)d_in[14];
    const float* Wl  = (const float*)d_in[15];
    const float* bl  = (const float*)d_in[16];
    float* outp = (float*)d_out;

    const int N = NN;
    const int E = in_sizes[1] / 2;
    const int G = out_size;

    // workspace carve-up (256B aligned)
    char* base = (char*)d_ws;
    size_t off = 0;
    auto alloc = [&](size_t bytes) { void* p = base + off; off = (off + bytes + 255) & ~(size_t)255; return p; };
    int*   flag    = (int*)  alloc(16);
    float* dinv    = (float*)alloc((size_t)N * 4);
    int*   counts  = (int*)  alloc((size_t)N * 4);
    int*   rp      = (int*)  alloc(((size_t)N + 1) * 4);
    int*   fillcnt = (int*)  alloc((size_t)N * 4);
    int*   partial = (int*)  alloc(1024);
    float* sc1     = (float*)alloc(HH * 4);
    float* sh1     = (float*)alloc(HH * 4);
    float* sc2     = (float*)alloc(HH * 4);
    float* sh2     = (float*)alloc(HH * 4);
    float* gsum    = (float*)alloc((size_t)G * 4);
    int*   gcnt    = (int*)  alloc((size_t)G * 4);
    int2*  cw      = (int2*) alloc((size_t)E * 8);
    unsigned short* hb1 = (unsigned short*)alloc((size_t)N * HH * 2);  // bf16 h
    unsigned short* hb2 = (unsigned short*)alloc((size_t)N * HH * 2);  // bf16 h
    (void)ws_size;

    // zero accumulators (fresh every call)
    hipMemsetAsync(counts, 0, (size_t)N * 4, stream);
    hipMemsetAsync(fillcnt, 0, (size_t)N * 4, stream);
    hipMemsetAsync(gsum, 0, (size_t)G * 4, stream);
    hipMemsetAsync(gcnt, 0, (size_t)G * 4, stream);

    k_detect<<<1, 64, 0, stream>>>((const unsigned*)ei, flag);

    int eb = (E + 255) / 256;
    k_count<<<eb, 256, 0, stream>>>(ei, E, flag, counts);

    int nb = (N + 255) / 256;
    k_dinv<<<nb, 256, 0, stream>>>(counts, dinv, bat, flag, gcnt, N);

    int nch = (N + 511) / 512;
    k_scan1<<<nch, 512, 0, stream>>>(counts, partial, N);
    k_scan2<<<1, 256, 0, stream>>>(partial, nch);
    k_scan3<<<nch, 512, 0, stream>>>(counts, partial, rp, N, E);

    k_fill<<<eb, 256, 0, stream>>>(ei, E, flag, dinv, rp, fillcnt, cw);

    k_prep<<<1, 64, 0, stream>>>(b1, g1, be1, m1, v1, b2, g2, be2, m2, v2,
                                 sc1, sh1, sc2, sh2);

    // layer 1: GEMM (f32 in -> bf16 out), agg (bf16 gather -> bf16 out)
    k_gemm<FF, 8, float><<<(N + 7) / 8, 512, 0, stream>>>(x, W1, hb1, N);
    k_agg<1><<<(N + 3) / 4, 256, 0, stream>>>(hb1, cw, rp, dinv, sc1, sh1, hb2,
                                              bat, flag, Wl, gsum, N);
    // layer 2: GEMM (bf16 in -> bf16 out), agg fused with pool
    k_gemm<HH, 8, unsigned short><<<(N + 7) / 8, 512, 0, stream>>>(hb2, W2, hb1, N);
    k_agg<2><<<(N + 3) / 4, 256, 0, stream>>>(hb1, cw, rp, dinv, sc2, sh2, nullptr,
                                              bat, flag, Wl, gsum, N);

    k_final<<<1, 256, 0, stream>>>(gsum, gcnt, bl, outp, G);
}